// Round 1
// baseline (824.458 us; speedup 1.0000x reference)
//
#include <hip/hip_runtime.h>
#include <math.h>

#define D 128
#define GR 32  // rows per GEMM block

// p[i] = dot(x[i], w_pred[0:128]); q[i] = dot(x[i], w_pred[128:256])
__global__ __launch_bounds__(256) void k_pq(const float* __restrict__ x,
                                            const float* __restrict__ w_pred,
                                            float* __restrict__ p, float* __restrict__ q,
                                            int n) {
  int wid = (blockIdx.x * blockDim.x + threadIdx.x) >> 6;  // one wave per row
  int lane = threadIdx.x & 63;
  if (wid >= n) return;
  float2 xv = ((const float2*)(x + (size_t)wid * D))[lane];
  float2 wp = ((const float2*)w_pred)[lane];
  float2 wq = ((const float2*)w_pred)[64 + lane];
  float pp = xv.x * wp.x + xv.y * wp.y;
  float qq = xv.x * wq.x + xv.y * wq.y;
#pragma unroll
  for (int off = 32; off > 0; off >>= 1) {
    pp += __shfl_down(pp, off);
    qq += __shfl_down(qq, off);
  }
  if (lane == 0) { p[wid] = pp; q[wid] = qq; }
}

__global__ __launch_bounds__(256) void k_initdeg(float* __restrict__ deg, int n) {
  int i = blockIdx.x * blockDim.x + threadIdx.x;
  if (i < n) deg[i] = 1.0f;  // self-loop weight
}

// ew[e] = sigmoid(p[src] + q[tgt] + b_pred); deg[tgt] += ew[e]
__global__ __launch_bounds__(256) void k_edgew(const int* __restrict__ src,
                                               const int* __restrict__ tgt,
                                               const float* __restrict__ p,
                                               const float* __restrict__ q,
                                               const float* __restrict__ b_pred,
                                               float* __restrict__ ew,
                                               float* __restrict__ deg, int E) {
  int e = blockIdx.x * blockDim.x + threadIdx.x;
  if (e >= E) return;
  int s = src[e], t = tgt[e];
  float z = p[s] + q[t] + b_pred[0];
  float w = 1.0f / (1.0f + expf(-z));
  ew[e] = w;
  atomicAdd(&deg[t], w);
}

// deg -> deg^{-1/2} in place
__global__ __launch_bounds__(256) void k_dis(float* __restrict__ deg, int n) {
  int i = blockIdx.x * blockDim.x + threadIdx.x;
  if (i < n) {
    float d = deg[i];
    deg[i] = (d > 0.0f) ? rsqrtf(d) : 0.0f;
  }
}

// xw = x @ W; out = dis^2 * xw + b   (self-loop term fused; out fully initialized here)
// W staged in LDS in two 32KB k-halves; each thread computes 4 rows x 4 cols.
__global__ __launch_bounds__(256) void k_gemm(const float* __restrict__ x,
                                              const float* __restrict__ W,
                                              const float* __restrict__ dis,
                                              const float* __restrict__ b,
                                              float* __restrict__ xw,
                                              float* __restrict__ out, int n) {
  __shared__ float Ws[64 * D];   // 32 KB: half of W (64 k-rows x 128 cols)
  __shared__ float xs[GR * D];   // 16 KB: 32 x-rows

  int row0 = blockIdx.x * GR;
  float4* xs4 = (float4*)xs;
  const float4* x4 = (const float4*)x;
  for (int i = threadIdx.x; i < GR * D / 4; i += 256) {
    int r = i >> 5;
    int gr = row0 + r;
    xs4[i] = (gr < n) ? x4[(size_t)gr * 32 + (i & 31)] : make_float4(0.f, 0.f, 0.f, 0.f);
  }

  int colg = threadIdx.x & 31;   // 32 col-groups of 4 columns
  int rowg = threadIdx.x >> 5;   // 8 row-groups of 4 rows
  float4 acc[4];
#pragma unroll
  for (int r = 0; r < 4; ++r) acc[r] = make_float4(0.f, 0.f, 0.f, 0.f);

  const float4* W4 = (const float4*)W;
  float4* Ws4 = (float4*)Ws;

  for (int half = 0; half < 2; ++half) {
    __syncthreads();
    for (int i = threadIdx.x; i < 64 * D / 4; i += 256)
      Ws4[i] = W4[half * (64 * D / 4) + i];
    __syncthreads();
#pragma unroll
    for (int k4 = 0; k4 < 16; ++k4) {
      float4 xv[4];
#pragma unroll
      for (int r = 0; r < 4; ++r)
        xv[r] = xs4[(rowg * 4 + r) * 32 + half * 16 + k4];
#pragma unroll
      for (int kk = 0; kk < 4; ++kk) {
        float4 w = Ws4[(k4 * 4 + kk) * 32 + colg];
#pragma unroll
        for (int r = 0; r < 4; ++r) {
          float xk = (&xv[r].x)[kk];
          acc[r].x = fmaf(xk, w.x, acc[r].x);
          acc[r].y = fmaf(xk, w.y, acc[r].y);
          acc[r].z = fmaf(xk, w.z, acc[r].z);
          acc[r].w = fmaf(xk, w.w, acc[r].w);
        }
      }
    }
  }

  float4 bb = ((const float4*)b)[colg];
#pragma unroll
  for (int r = 0; r < 4; ++r) {
    int gr = row0 + rowg * 4 + r;
    if (gr < n) {
      ((float4*)xw)[(size_t)gr * 32 + colg] = acc[r];
      float dv = dis[gr];
      float s = dv * dv;
      float4 o;
      o.x = fmaf(acc[r].x, s, bb.x);
      o.y = fmaf(acc[r].y, s, bb.y);
      o.z = fmaf(acc[r].z, s, bb.z);
      o.w = fmaf(acc[r].w, s, bb.w);
      ((float4*)out)[(size_t)gr * 32 + colg] = o;
    }
  }
}

// One wave per edge: out[tgt] += dis[src]*ew*dis[tgt] * xw[src]
__global__ __launch_bounds__(256) void k_scatter(const int* __restrict__ src,
                                                 const int* __restrict__ tgt,
                                                 const float* __restrict__ ew,
                                                 const float* __restrict__ dis,
                                                 const float* __restrict__ xw,
                                                 float* __restrict__ out, int E) {
  int wid = (blockIdx.x * blockDim.x + threadIdx.x) >> 6;
  int lane = threadIdx.x & 63;
  if (wid >= E) return;
  int s = src[wid], t = tgt[wid];
  float nrm = dis[s] * ew[wid] * dis[t];
  float2 v = ((const float2*)(xw + (size_t)s * D))[lane];
  float* op = out + (size_t)t * D + lane * 2;
  atomicAdd(op, v.x * nrm);
  atomicAdd(op + 1, v.y * nrm);
}

extern "C" void kernel_launch(void* const* d_in, const int* in_sizes, int n_in,
                              void* d_out, int out_size, void* d_ws, size_t ws_size,
                              hipStream_t stream) {
  const float* x      = (const float*)d_in[0];
  const int*   ei     = (const int*)d_in[1];
  const float* W      = (const float*)d_in[2];
  const float* b      = (const float*)d_in[3];
  const float* w_pred = (const float*)d_in[4];
  const float* b_pred = (const float*)d_in[5];

  int n = in_sizes[0] / D;
  int E = in_sizes[1] / 2;
  const int* src = ei;       // edge_index[0]
  const int* tgt = ei + E;   // edge_index[1]

  float* out = (float*)d_out;
  float* ws  = (float*)d_ws;
  float* xw  = ws;                          // n*D floats
  float* p   = xw + (size_t)n * D;          // n
  float* q   = p + n;                       // n
  float* deg = q + n;                       // n (becomes dis in-place)
  float* ew  = deg + n;                     // E

  k_pq<<<(n + 3) / 4, 256, 0, stream>>>(x, w_pred, p, q, n);
  k_initdeg<<<(n + 255) / 256, 256, 0, stream>>>(deg, n);
  k_edgew<<<(E + 255) / 256, 256, 0, stream>>>(src, tgt, p, q, b_pred, ew, deg, E);
  k_dis<<<(n + 255) / 256, 256, 0, stream>>>(deg, n);
  k_gemm<<<(n + GR - 1) / GR, 256, 0, stream>>>(x, W, deg, b, xw, out, n);
  k_scatter<<<(E + 3) / 4, 256, 0, stream>>>(src, tgt, ew, deg, xw, out, E);
}

// Round 2
// 316.000 us; speedup vs baseline: 2.6090x; 2.6090x over previous
//
#include <hip/hip_runtime.h>
#include <math.h>

#define D 128
#define GR 32  // rows per GEMM block

// p[i] = dot(x[i], w_pred[0:128]); q[i] = dot(x[i], w_pred[128:256])
__global__ __launch_bounds__(256) void k_pq(const float* __restrict__ x,
                                            const float* __restrict__ w_pred,
                                            float* __restrict__ p, float* __restrict__ q,
                                            int n) {
  int wid = (blockIdx.x * blockDim.x + threadIdx.x) >> 6;  // one wave per row
  int lane = threadIdx.x & 63;
  if (wid >= n) return;
  float2 xv = ((const float2*)(x + (size_t)wid * D))[lane];
  float2 wp = ((const float2*)w_pred)[lane];
  float2 wq = ((const float2*)w_pred)[64 + lane];
  float pp = xv.x * wp.x + xv.y * wp.y;
  float qq = xv.x * wq.x + xv.y * wq.y;
#pragma unroll
  for (int off = 32; off > 0; off >>= 1) {
    pp += __shfl_down(pp, off);
    qq += __shfl_down(qq, off);
  }
  if (lane == 0) { p[wid] = pp; q[wid] = qq; }
}

// deg=1 (self-loop), cnt=0
__global__ __launch_bounds__(256) void k_init(float* __restrict__ deg,
                                              int* __restrict__ cnt, int n) {
  int i = blockIdx.x * blockDim.x + threadIdx.x;
  if (i < n) { deg[i] = 1.0f; cnt[i] = 0; }
}

// ew[e] = sigmoid(p[src]+q[tgt]+b_pred); deg[tgt]+=ew; cnt[tgt]+=1
__global__ __launch_bounds__(256) void k_edgew(const int* __restrict__ src,
                                               const int* __restrict__ tgt,
                                               const float* __restrict__ p,
                                               const float* __restrict__ q,
                                               const float* __restrict__ b_pred,
                                               float* __restrict__ ew,
                                               float* __restrict__ deg,
                                               int* __restrict__ cnt, int E) {
  int e = blockIdx.x * blockDim.x + threadIdx.x;
  if (e >= E) return;
  int s = src[e], t = tgt[e];
  float z = p[s] + q[t] + b_pred[0];
  float w = 1.0f / (1.0f + expf(-z));
  ew[e] = w;
  atomicAdd(&deg[t], w);
  atomicAdd(&cnt[t], 1);
}

// deg -> deg^{-1/2} in place
__global__ __launch_bounds__(256) void k_dis(float* __restrict__ deg, int n) {
  int i = blockIdx.x * blockDim.x + threadIdx.x;
  if (i < n) {
    float d = deg[i];
    deg[i] = (d > 0.0f) ? rsqrtf(d) : 0.0f;
  }
}

// ---- 3-kernel exclusive scan of cnt[n] -> rowptr[n] (+ rowptr[n]=E) ----
// scan1: each block scans 1024 elements (256 thr x 4), writes per-element
// exclusive scan into rowptr and block total into bsum[b].
__global__ __launch_bounds__(256) void k_scan1(const int* __restrict__ cnt,
                                               int* __restrict__ rowptr,
                                               int* __restrict__ bsum, int n) {
  __shared__ int wsum[4];
  int base = blockIdx.x * 1024 + threadIdx.x * 4;
  int4 v = make_int4(0, 0, 0, 0);
  if (base + 3 < n) v = *(const int4*)(cnt + base);
  else {
    if (base + 0 < n) v.x = cnt[base + 0];
    if (base + 1 < n) v.y = cnt[base + 1];
    if (base + 2 < n) v.z = cnt[base + 2];
    if (base + 3 < n) v.w = cnt[base + 3];
  }
  int s = v.x + v.y + v.z + v.w;
  int lane = threadIdx.x & 63;
  int wave = threadIdx.x >> 6;
  int incl = s;
#pragma unroll
  for (int off = 1; off < 64; off <<= 1) {
    int t = __shfl_up(incl, off);
    if (lane >= off) incl += t;
  }
  if (lane == 63) wsum[wave] = incl;
  __syncthreads();
  int woff = 0;
#pragma unroll
  for (int w = 0; w < 4; ++w) if (w < wave) woff += wsum[w];
  int excl = woff + incl - s;
  if (base + 0 < n) rowptr[base + 0] = excl;
  if (base + 1 < n) rowptr[base + 1] = excl + v.x;
  if (base + 2 < n) rowptr[base + 2] = excl + v.x + v.y;
  if (base + 3 < n) rowptr[base + 3] = excl + v.x + v.y + v.z;
  if (threadIdx.x == 255) bsum[blockIdx.x] = woff + incl;
}

// scan2: single wave exclusive-scans bsum[nb] (nb<=64) -> bpre
__global__ __launch_bounds__(64) void k_scan2(const int* __restrict__ bsum,
                                              int* __restrict__ bpre, int nb) {
  int lane = threadIdx.x;
  int v = (lane < nb) ? bsum[lane] : 0;
  int incl = v;
#pragma unroll
  for (int off = 1; off < 64; off <<= 1) {
    int t = __shfl_up(incl, off);
    if (lane >= off) incl += t;
  }
  if (lane < nb) bpre[lane] = incl - v;
}

// scan3: rowptr[i]+=bpre[i/1024]; cursor[i]=rowptr[i]; rowptr[n]=E
__global__ __launch_bounds__(256) void k_scan3(int* __restrict__ rowptr,
                                               const int* __restrict__ bpre,
                                               int* __restrict__ cursor,
                                               int n, int E) {
  int i = blockIdx.x * blockDim.x + threadIdx.x;
  if (i < n) {
    int r = rowptr[i] + bpre[i >> 10];
    rowptr[i] = r;
    cursor[i] = r;
  }
  if (i == 0) rowptr[n] = E;
}

// fill: epair[pos] = (src, coef) in CSR order by tgt
__global__ __launch_bounds__(256) void k_fill(const int* __restrict__ src,
                                              const int* __restrict__ tgt,
                                              const float* __restrict__ ew,
                                              const float* __restrict__ dis,
                                              int* __restrict__ cursor,
                                              int2* __restrict__ epair, int E) {
  int e = blockIdx.x * blockDim.x + threadIdx.x;
  if (e >= E) return;
  int s = src[e], t = tgt[e];
  float c = dis[s] * ew[e] * dis[t];
  int pos = atomicAdd(&cursor[t], 1);
  epair[pos] = make_int2(s, __float_as_int(c));
}

// xw = x @ W; out = dis^2 * xw + b   (self-loop term fused)
__global__ __launch_bounds__(256) void k_gemm(const float* __restrict__ x,
                                              const float* __restrict__ W,
                                              const float* __restrict__ dis,
                                              const float* __restrict__ b,
                                              float* __restrict__ xw,
                                              float* __restrict__ out, int n) {
  __shared__ float Ws[64 * D];   // 32 KB: half of W
  __shared__ float xs[GR * D];   // 16 KB: 32 x-rows

  int row0 = blockIdx.x * GR;
  float4* xs4 = (float4*)xs;
  const float4* x4 = (const float4*)x;
  for (int i = threadIdx.x; i < GR * D / 4; i += 256) {
    int r = i >> 5;
    int gr = row0 + r;
    xs4[i] = (gr < n) ? x4[(size_t)gr * 32 + (i & 31)] : make_float4(0.f, 0.f, 0.f, 0.f);
  }

  int colg = threadIdx.x & 31;
  int rowg = threadIdx.x >> 5;
  float4 acc[4];
#pragma unroll
  for (int r = 0; r < 4; ++r) acc[r] = make_float4(0.f, 0.f, 0.f, 0.f);

  const float4* W4 = (const float4*)W;
  float4* Ws4 = (float4*)Ws;

  for (int half = 0; half < 2; ++half) {
    __syncthreads();
    for (int i = threadIdx.x; i < 64 * D / 4; i += 256)
      Ws4[i] = W4[half * (64 * D / 4) + i];
    __syncthreads();
#pragma unroll
    for (int k4 = 0; k4 < 16; ++k4) {
      float4 xv[4];
#pragma unroll
      for (int r = 0; r < 4; ++r)
        xv[r] = xs4[(rowg * 4 + r) * 32 + half * 16 + k4];
#pragma unroll
      for (int kk = 0; kk < 4; ++kk) {
        float4 w = Ws4[(k4 * 4 + kk) * 32 + colg];
#pragma unroll
        for (int r = 0; r < 4; ++r) {
          float xk = (&xv[r].x)[kk];
          acc[r].x = fmaf(xk, w.x, acc[r].x);
          acc[r].y = fmaf(xk, w.y, acc[r].y);
          acc[r].z = fmaf(xk, w.z, acc[r].z);
          acc[r].w = fmaf(xk, w.w, acc[r].w);
        }
      }
    }
  }

  float4 bb = ((const float4*)b)[colg];
#pragma unroll
  for (int r = 0; r < 4; ++r) {
    int gr = row0 + rowg * 4 + r;
    if (gr < n) {
      ((float4*)xw)[(size_t)gr * 32 + colg] = acc[r];
      float dv = dis[gr];
      float s = dv * dv;
      float4 o;
      o.x = fmaf(acc[r].x, s, bb.x);
      o.y = fmaf(acc[r].y, s, bb.y);
      o.z = fmaf(acc[r].z, s, bb.z);
      o.w = fmaf(acc[r].w, s, bb.w);
      ((float4*)out)[(size_t)gr * 32 + colg] = o;
    }
  }
}

// One wave per target node: out[t] += sum_j coef_j * xw[src_j]  (no atomics)
__global__ __launch_bounds__(256) void k_gather(const int* __restrict__ rowptr,
                                                const int2* __restrict__ epair,
                                                const float* __restrict__ xw,
                                                float* __restrict__ out, int n) {
  int wid = (blockIdx.x * blockDim.x + threadIdx.x) >> 6;
  int lane = threadIdx.x & 63;
  if (wid >= n) return;
  int beg = rowptr[wid], end = rowptr[wid + 1];
  const float2* xw2 = (const float2*)xw;
  float2* out2 = (float2*)out;
  float2 acc = out2[(size_t)wid * 64 + lane];  // self-loop + bias from k_gemm
  for (int j0 = beg; j0 < end; j0 += 64) {
    int m = end - j0; if (m > 64) m = 64;
    int2 pr = make_int2(0, 0);
    if (lane < m) pr = epair[j0 + lane];
#pragma unroll 4
    for (int k = 0; k < m; ++k) {
      int s = __shfl(pr.x, k);
      float c = __int_as_float(__shfl(pr.y, k));
      float2 v = xw2[(size_t)s * 64 + lane];
      acc.x = fmaf(c, v.x, acc.x);
      acc.y = fmaf(c, v.y, acc.y);
    }
  }
  out2[(size_t)wid * 64 + lane] = acc;
}

extern "C" void kernel_launch(void* const* d_in, const int* in_sizes, int n_in,
                              void* d_out, int out_size, void* d_ws, size_t ws_size,
                              hipStream_t stream) {
  const float* x      = (const float*)d_in[0];
  const int*   ei     = (const int*)d_in[1];
  const float* W      = (const float*)d_in[2];
  const float* b      = (const float*)d_in[3];
  const float* w_pred = (const float*)d_in[4];
  const float* b_pred = (const float*)d_in[5];

  int n = in_sizes[0] / D;
  int E = in_sizes[1] / 2;
  const int* src = ei;       // edge_index[0]
  const int* tgt = ei + E;   // edge_index[1]

  float* out = (float*)d_out;
  float* ws  = (float*)d_ws;
  // workspace layout (floats/ints, 4B each)
  float* xw     = ws;                          // n*D
  float* p      = xw + (size_t)n * D;          // n
  float* q      = p + n;                       // n
  float* deg    = q + n;                       // n (becomes dis in place)
  float* ew     = deg + n;                     // E
  int2*  epair  = (int2*)(ew + E);             // E pairs (2E words)
  int*   cnt    = (int*)(epair + E);           // n (histogram, then cursor)
  int*   rowptr = cnt + n;                     // n+1
  int*   bsum   = rowptr + n + 1;              // 64
  int*   bpre   = bsum + 64;                   // 64

  int nb = (n + 1023) / 1024;  // scan blocks

  k_pq<<<(n + 3) / 4, 256, 0, stream>>>(x, w_pred, p, q, n);
  k_init<<<(n + 255) / 256, 256, 0, stream>>>(deg, cnt, n);
  k_edgew<<<(E + 255) / 256, 256, 0, stream>>>(src, tgt, p, q, b_pred, ew, deg, cnt, E);
  k_dis<<<(n + 255) / 256, 256, 0, stream>>>(deg, n);
  k_scan1<<<nb, 256, 0, stream>>>(cnt, rowptr, bsum, n);
  k_scan2<<<1, 64, 0, stream>>>(bsum, bpre, nb);
  k_scan3<<<(n + 255) / 256, 256, 0, stream>>>(rowptr, bpre, cnt, n, E);
  k_fill<<<(E + 255) / 256, 256, 0, stream>>>(src, tgt, ew, deg, cnt, epair, E);
  k_gemm<<<(n + GR - 1) / GR, 256, 0, stream>>>(x, W, deg, b, xw, out, n);
  k_gather<<<(n + 3) / 4, 256, 0, stream>>>(rowptr, epair, xw, out, n);
}

// Round 3
// 282.843 us; speedup vs baseline: 2.9149x; 1.1172x over previous
//
#include <hip/hip_runtime.h>
#include <math.h>

#define D 128
#define GR 32   // rows per GEMM block
#define NC 16   // privatized histogram/cursor copies

// p[i] = dot(x[i], w_pred[0:128]); q[i] = dot(x[i], w_pred[128:256])
__global__ __launch_bounds__(256) void k_pq(const float* __restrict__ x,
                                            const float* __restrict__ w_pred,
                                            float* __restrict__ p, float* __restrict__ q,
                                            int n) {
  int wid = (blockIdx.x * blockDim.x + threadIdx.x) >> 6;  // one wave per row
  int lane = threadIdx.x & 63;
  if (wid >= n) return;
  float2 xv = ((const float2*)(x + (size_t)wid * D))[lane];
  float2 wp = ((const float2*)w_pred)[lane];
  float2 wq = ((const float2*)w_pred)[64 + lane];
  float pp = xv.x * wp.x + xv.y * wp.y;
  float qq = xv.x * wq.x + xv.y * wq.y;
#pragma unroll
  for (int off = 32; off > 0; off >>= 1) {
    pp += __shfl_down(pp, off);
    qq += __shfl_down(qq, off);
  }
  if (lane == 0) { p[wid] = pp; q[wid] = qq; }
}

// ew[e] = sigmoid(p[src]+q[tgt]+b_pred); privatized histogram partial[c][tgt]++
__global__ __launch_bounds__(256) void k_ew_hist(const int* __restrict__ src,
                                                 const int* __restrict__ tgt,
                                                 const float* __restrict__ p,
                                                 const float* __restrict__ q,
                                                 const float* __restrict__ b_pred,
                                                 float* __restrict__ ew,
                                                 int* __restrict__ partial,
                                                 int E, int n) {
  int e = blockIdx.x * blockDim.x + threadIdx.x;
  if (e >= E) return;
  int s = src[e], t = tgt[e];
  float z = p[s] + q[t] + b_pred[0];
  ew[e] = 1.0f / (1.0f + expf(-z));
  int c = (e >> 8) & (NC - 1);
  atomicAdd(&partial[c * n + t], 1);
}

// cnt[t] = sum_c partial[c][t]
__global__ __launch_bounds__(256) void k_reduce(const int* __restrict__ partial,
                                                int* __restrict__ cnt, int n) {
  int t = blockIdx.x * blockDim.x + threadIdx.x;
  if (t >= n) return;
  int s = 0;
#pragma unroll
  for (int c = 0; c < NC; ++c) s += partial[c * n + t];
  cnt[t] = s;
}

// scan1: each block scans 1024 elements (256 thr x 4) -> exclusive scan + block sum
__global__ __launch_bounds__(256) void k_scan1(const int* __restrict__ cnt,
                                               int* __restrict__ rowptr,
                                               int* __restrict__ bsum, int n) {
  __shared__ int wsum[4];
  int base = blockIdx.x * 1024 + threadIdx.x * 4;
  int4 v = make_int4(0, 0, 0, 0);
  if (base + 3 < n) v = *(const int4*)(cnt + base);
  else {
    if (base + 0 < n) v.x = cnt[base + 0];
    if (base + 1 < n) v.y = cnt[base + 1];
    if (base + 2 < n) v.z = cnt[base + 2];
    if (base + 3 < n) v.w = cnt[base + 3];
  }
  int s = v.x + v.y + v.z + v.w;
  int lane = threadIdx.x & 63;
  int wave = threadIdx.x >> 6;
  int incl = s;
#pragma unroll
  for (int off = 1; off < 64; off <<= 1) {
    int t = __shfl_up(incl, off);
    if (lane >= off) incl += t;
  }
  if (lane == 63) wsum[wave] = incl;
  __syncthreads();
  int woff = 0;
#pragma unroll
  for (int w = 0; w < 4; ++w) if (w < wave) woff += wsum[w];
  int excl = woff + incl - s;
  if (base + 0 < n) rowptr[base + 0] = excl;
  if (base + 1 < n) rowptr[base + 1] = excl + v.x;
  if (base + 2 < n) rowptr[base + 2] = excl + v.x + v.y;
  if (base + 3 < n) rowptr[base + 3] = excl + v.x + v.y + v.z;
  if (threadIdx.x == 255) bsum[blockIdx.x] = woff + incl;
}

// scan2: single wave exclusive-scans bsum[nb] (nb<=64)
__global__ __launch_bounds__(64) void k_scan2(const int* __restrict__ bsum,
                                              int* __restrict__ bpre, int nb) {
  int lane = threadIdx.x;
  int v = (lane < nb) ? bsum[lane] : 0;
  int incl = v;
#pragma unroll
  for (int off = 1; off < 64; off <<= 1) {
    int t = __shfl_up(incl, off);
    if (lane >= off) incl += t;
  }
  if (lane < nb) bpre[lane] = incl - v;
}

// cursors: finalize rowptr; cursor[c][t] = disjoint sub-range start for copy c
__global__ __launch_bounds__(256) void k_cursors(int* __restrict__ rowptr,
                                                 const int* __restrict__ bpre,
                                                 const int* __restrict__ partial,
                                                 int* __restrict__ cursor,
                                                 int n, int E) {
  int t = blockIdx.x * blockDim.x + threadIdx.x;
  if (t < n) {
    int r = rowptr[t] + bpre[t >> 10];
    rowptr[t] = r;
#pragma unroll
    for (int c = 0; c < NC; ++c) {
      cursor[c * n + t] = r;
      r += partial[c * n + t];
    }
  }
  if (t == 0) rowptr[n] = E;
}

// fill: epair[pos] = (src, ew) in CSR order by tgt, privatized cursors
__global__ __launch_bounds__(256) void k_fill(const int* __restrict__ src,
                                              const int* __restrict__ tgt,
                                              const float* __restrict__ ew,
                                              int* __restrict__ cursor,
                                              int2* __restrict__ epair, int E, int n) {
  int e = blockIdx.x * blockDim.x + threadIdx.x;
  if (e >= E) return;
  int s = src[e], t = tgt[e];
  int c = (e >> 8) & (NC - 1);
  int pos = atomicAdd(&cursor[c * n + t], 1);
  epair[pos] = make_int2(s, __float_as_int(ew[e]));
}

// deg[t] = 1 + segmented sum of ew over CSR range; dis = rsqrt(deg)
__global__ __launch_bounds__(256) void k_deg(const int* __restrict__ rowptr,
                                             const int2* __restrict__ epair,
                                             float* __restrict__ dis, int n) {
  int t = blockIdx.x * blockDim.x + threadIdx.x;
  if (t >= n) return;
  int beg = rowptr[t], end = rowptr[t + 1];
  float s = 1.0f;  // self-loop weight
  for (int j = beg; j < end; ++j) s += __int_as_float(epair[j].y);
  dis[t] = (s > 0.0f) ? rsqrtf(s) : 0.0f;
}

// xw2 = dis[row] * (x @ W)
__global__ __launch_bounds__(256) void k_gemm(const float* __restrict__ x,
                                              const float* __restrict__ W,
                                              const float* __restrict__ dis,
                                              float* __restrict__ xw2, int n) {
  __shared__ float Ws[64 * D];   // 32 KB: half of W
  __shared__ float xs[GR * D];   // 16 KB: 32 x-rows

  int row0 = blockIdx.x * GR;
  float4* xs4 = (float4*)xs;
  const float4* x4 = (const float4*)x;
  for (int i = threadIdx.x; i < GR * D / 4; i += 256) {
    int r = i >> 5;
    int gr = row0 + r;
    xs4[i] = (gr < n) ? x4[(size_t)gr * 32 + (i & 31)] : make_float4(0.f, 0.f, 0.f, 0.f);
  }

  int colg = threadIdx.x & 31;
  int rowg = threadIdx.x >> 5;
  float4 acc[4];
#pragma unroll
  for (int r = 0; r < 4; ++r) acc[r] = make_float4(0.f, 0.f, 0.f, 0.f);

  const float4* W4 = (const float4*)W;
  float4* Ws4 = (float4*)Ws;

  for (int half = 0; half < 2; ++half) {
    __syncthreads();
    for (int i = threadIdx.x; i < 64 * D / 4; i += 256)
      Ws4[i] = W4[half * (64 * D / 4) + i];
    __syncthreads();
#pragma unroll
    for (int k4 = 0; k4 < 16; ++k4) {
      float4 xv[4];
#pragma unroll
      for (int r = 0; r < 4; ++r)
        xv[r] = xs4[(rowg * 4 + r) * 32 + half * 16 + k4];
#pragma unroll
      for (int kk = 0; kk < 4; ++kk) {
        float4 w = Ws4[(k4 * 4 + kk) * 32 + colg];
#pragma unroll
        for (int r = 0; r < 4; ++r) {
          float xk = (&xv[r].x)[kk];
          acc[r].x = fmaf(xk, w.x, acc[r].x);
          acc[r].y = fmaf(xk, w.y, acc[r].y);
          acc[r].z = fmaf(xk, w.z, acc[r].z);
          acc[r].w = fmaf(xk, w.w, acc[r].w);
        }
      }
    }
  }

#pragma unroll
  for (int r = 0; r < 4; ++r) {
    int gr = row0 + rowg * 4 + r;
    if (gr < n) {
      float dv = dis[gr];
      float4 o;
      o.x = acc[r].x * dv; o.y = acc[r].y * dv;
      o.z = acc[r].z * dv; o.w = acc[r].w * dv;
      ((float4*)xw2)[(size_t)gr * 32 + colg] = o;
    }
  }
}

// One wave per node: out[t] = dis[t]*(xw2[t] + sum_j ew_j * xw2[src_j]) + b
__global__ __launch_bounds__(256) void k_gather(const int* __restrict__ rowptr,
                                                const int2* __restrict__ epair,
                                                const float* __restrict__ xw2,
                                                const float* __restrict__ dis,
                                                const float* __restrict__ b,
                                                float* __restrict__ out, int n) {
  int wid = (blockIdx.x * blockDim.x + threadIdx.x) >> 6;
  int lane = threadIdx.x & 63;
  if (wid >= n) return;
  int beg = rowptr[wid], end = rowptr[wid + 1];
  const float2* xw22 = (const float2*)xw2;
  float2 acc = xw22[(size_t)wid * 64 + lane];  // self-loop term
  for (int j0 = beg; j0 < end; j0 += 64) {
    int m = end - j0; if (m > 64) m = 64;
    int2 pr = make_int2(0, 0);
    if (lane < m) pr = epair[j0 + lane];
#pragma unroll 4
    for (int k = 0; k < m; ++k) {
      int s = __shfl(pr.x, k);
      float c = __int_as_float(__shfl(pr.y, k));
      float2 v = xw22[(size_t)s * 64 + lane];
      acc.x = fmaf(c, v.x, acc.x);
      acc.y = fmaf(c, v.y, acc.y);
    }
  }
  float dt = dis[wid];
  float2 bb = ((const float2*)b)[lane];
  float2 o;
  o.x = fmaf(dt, acc.x, bb.x);
  o.y = fmaf(dt, acc.y, bb.y);
  ((float2*)out)[(size_t)wid * 64 + lane] = o;
}

extern "C" void kernel_launch(void* const* d_in, const int* in_sizes, int n_in,
                              void* d_out, int out_size, void* d_ws, size_t ws_size,
                              hipStream_t stream) {
  const float* x      = (const float*)d_in[0];
  const int*   ei     = (const int*)d_in[1];
  const float* W      = (const float*)d_in[2];
  const float* b      = (const float*)d_in[3];
  const float* w_pred = (const float*)d_in[4];
  const float* b_pred = (const float*)d_in[5];

  int n = in_sizes[0] / D;
  int E = in_sizes[1] / 2;
  const int* src = ei;       // edge_index[0]
  const int* tgt = ei + E;   // edge_index[1]

  float* out = (float*)d_out;
  float* ws  = (float*)d_ws;
  // workspace layout (4B words)
  float* xw2     = ws;                          // n*D
  float* p       = xw2 + (size_t)n * D;         // n
  float* q       = p + n;                       // n
  float* dis     = q + n;                       // n
  float* ew      = dis + n;                     // E
  int2*  epair   = (int2*)(ew + E);             // E pairs (2E words)
  int*   partial = (int*)(epair + E);           // NC*n
  int*   cursor  = partial + (size_t)NC * n;    // NC*n
  int*   cnt     = cursor + (size_t)NC * n;     // n
  int*   rowptr  = cnt + n;                     // n+1
  int*   bsum    = rowptr + n + 1;              // 64
  int*   bpre    = bsum + 64;                   // 64

  int nb = (n + 1023) / 1024;  // scan blocks (<=64 for n<=65536)

  hipMemsetAsync(partial, 0, (size_t)NC * n * sizeof(int), stream);
  k_pq<<<(n + 3) / 4, 256, 0, stream>>>(x, w_pred, p, q, n);
  k_ew_hist<<<(E + 255) / 256, 256, 0, stream>>>(src, tgt, p, q, b_pred, ew, partial, E, n);
  k_reduce<<<(n + 255) / 256, 256, 0, stream>>>(partial, cnt, n);
  k_scan1<<<nb, 256, 0, stream>>>(cnt, rowptr, bsum, n);
  k_scan2<<<1, 64, 0, stream>>>(bsum, bpre, nb);
  k_cursors<<<(n + 255) / 256, 256, 0, stream>>>(rowptr, bpre, partial, cursor, n, E);
  k_fill<<<(E + 255) / 256, 256, 0, stream>>>(src, tgt, ew, cursor, epair, E, n);
  k_deg<<<(n + 255) / 256, 256, 0, stream>>>(rowptr, epair, dis, n);
  k_gemm<<<(n + GR - 1) / GR, 256, 0, stream>>>(x, W, dis, xw2, n);
  k_gather<<<(n + 3) / 4, 256, 0, stream>>>(rowptr, epair, xw2, dis, b, out, n);
}

// Round 4
// 246.639 us; speedup vs baseline: 3.3428x; 1.1468x over previous
//
#include <hip/hip_runtime.h>
#include <math.h>

#define D 128
#define GR 32   // rows per GEMM block
#define NC 16   // privatized histogram copies

__device__ __forceinline__ unsigned int bf16_round(float f) {
  unsigned int u = __float_as_uint(f);
  return (u + 0x7fffu + ((u >> 16) & 1u)) >> 16;  // RNE
}

// p[i] = dot(x[i], w_pred[0:128]); q[i] = dot(x[i], w_pred[128:256])
__global__ __launch_bounds__(256) void k_pq(const float* __restrict__ x,
                                            const float* __restrict__ w_pred,
                                            float* __restrict__ p, float* __restrict__ q,
                                            int n) {
  int wid = (blockIdx.x * blockDim.x + threadIdx.x) >> 6;  // one wave per row
  int lane = threadIdx.x & 63;
  if (wid >= n) return;
  float2 xv = ((const float2*)(x + (size_t)wid * D))[lane];
  float2 wp = ((const float2*)w_pred)[lane];
  float2 wq = ((const float2*)w_pred)[64 + lane];
  float pp = xv.x * wp.x + xv.y * wp.y;
  float qq = xv.x * wq.x + xv.y * wq.y;
#pragma unroll
  for (int off = 32; off > 0; off >>= 1) {
    pp += __shfl_down(pp, off);
    qq += __shfl_down(qq, off);
  }
  if (lane == 0) { p[wid] = pp; q[wid] = qq; }
}

// ew[e] = sigmoid(p[src]+q[tgt]+b_pred); rank[e] = my index within (copy,tgt) cell
__global__ __launch_bounds__(256) void k_ew_hist(const int* __restrict__ src,
                                                 const int* __restrict__ tgt,
                                                 const float* __restrict__ p,
                                                 const float* __restrict__ q,
                                                 const float* __restrict__ b_pred,
                                                 float* __restrict__ ew,
                                                 int* __restrict__ rank,
                                                 int* __restrict__ partial,
                                                 int E, int n) {
  int e = blockIdx.x * blockDim.x + threadIdx.x;
  if (e >= E) return;
  int s = src[e], t = tgt[e];
  float z = p[s] + q[t] + b_pred[0];
  ew[e] = 1.0f / (1.0f + expf(-z));
  int c = (e >> 8) & (NC - 1);
  rank[e] = atomicAdd(&partial[c * n + t], 1);
}

// cnt[t] = sum_c partial[c][t]
__global__ __launch_bounds__(256) void k_reduce(const int* __restrict__ partial,
                                                int* __restrict__ cnt, int n) {
  int t = blockIdx.x * blockDim.x + threadIdx.x;
  if (t >= n) return;
  int s = 0;
#pragma unroll
  for (int c = 0; c < NC; ++c) s += partial[c * n + t];
  cnt[t] = s;
}

// scan1: each block scans 1024 elements (256 thr x 4) -> exclusive scan + block sum
__global__ __launch_bounds__(256) void k_scan1(const int* __restrict__ cnt,
                                               int* __restrict__ rowptr,
                                               int* __restrict__ bsum, int n) {
  __shared__ int wsum[4];
  int base = blockIdx.x * 1024 + threadIdx.x * 4;
  int4 v = make_int4(0, 0, 0, 0);
  if (base + 3 < n) v = *(const int4*)(cnt + base);
  else {
    if (base + 0 < n) v.x = cnt[base + 0];
    if (base + 1 < n) v.y = cnt[base + 1];
    if (base + 2 < n) v.z = cnt[base + 2];
    if (base + 3 < n) v.w = cnt[base + 3];
  }
  int s = v.x + v.y + v.z + v.w;
  int lane = threadIdx.x & 63;
  int wave = threadIdx.x >> 6;
  int incl = s;
#pragma unroll
  for (int off = 1; off < 64; off <<= 1) {
    int t = __shfl_up(incl, off);
    if (lane >= off) incl += t;
  }
  if (lane == 63) wsum[wave] = incl;
  __syncthreads();
  int woff = 0;
#pragma unroll
  for (int w = 0; w < 4; ++w) if (w < wave) woff += wsum[w];
  int excl = woff + incl - s;
  if (base + 0 < n) rowptr[base + 0] = excl;
  if (base + 1 < n) rowptr[base + 1] = excl + v.x;
  if (base + 2 < n) rowptr[base + 2] = excl + v.x + v.y;
  if (base + 3 < n) rowptr[base + 3] = excl + v.x + v.y + v.z;
  if (threadIdx.x == 255) bsum[blockIdx.x] = woff + incl;
}

// scan2: single wave exclusive-scans bsum[nb] (nb<=64)
__global__ __launch_bounds__(64) void k_scan2(const int* __restrict__ bsum,
                                              int* __restrict__ bpre, int nb) {
  int lane = threadIdx.x;
  int v = (lane < nb) ? bsum[lane] : 0;
  int incl = v;
#pragma unroll
  for (int off = 1; off < 64; off <<= 1) {
    int t = __shfl_up(incl, off);
    if (lane >= off) incl += t;
  }
  if (lane < nb) bpre[lane] = incl - v;
}

// cursors: finalize rowptr; cursor[c][t] = read-only base of copy c's sub-range
__global__ __launch_bounds__(256) void k_cursors(int* __restrict__ rowptr,
                                                 const int* __restrict__ bpre,
                                                 const int* __restrict__ partial,
                                                 int* __restrict__ cursor,
                                                 int n, int E) {
  int t = blockIdx.x * blockDim.x + threadIdx.x;
  if (t < n) {
    int r = rowptr[t] + bpre[t >> 10];
    rowptr[t] = r;
#pragma unroll
    for (int c = 0; c < NC; ++c) {
      cursor[c * n + t] = r;
      r += partial[c * n + t];
    }
  }
  if (t == 0) rowptr[n] = E;
}

// fill (NO atomics): epair[cursor_base + rank] = (src, ew)
__global__ __launch_bounds__(256) void k_fill(const int* __restrict__ src,
                                              const int* __restrict__ tgt,
                                              const float* __restrict__ ew,
                                              const int* __restrict__ rank,
                                              const int* __restrict__ cursor,
                                              int2* __restrict__ epair, int E, int n) {
  int e = blockIdx.x * blockDim.x + threadIdx.x;
  if (e >= E) return;
  int s = src[e], t = tgt[e];
  int c = (e >> 8) & (NC - 1);
  int pos = cursor[c * n + t] + rank[e];
  epair[pos] = make_int2(s, __float_as_int(ew[e]));
}

// deg[t] = 1 + segmented sum of ew over CSR range; dis = rsqrt(deg)
__global__ __launch_bounds__(256) void k_deg(const int* __restrict__ rowptr,
                                             const int2* __restrict__ epair,
                                             float* __restrict__ dis, int n) {
  int t = blockIdx.x * blockDim.x + threadIdx.x;
  if (t >= n) return;
  int beg = rowptr[t], end = rowptr[t + 1];
  float s = 1.0f;  // self-loop weight
  for (int j = beg; j < end; ++j) s += __int_as_float(epair[j].y);
  dis[t] = (s > 0.0f) ? rsqrtf(s) : 0.0f;
}

// xwh = bf16( dis[row] * (x @ W) )   -- 256 B/row
__global__ __launch_bounds__(256) void k_gemm(const float* __restrict__ x,
                                              const float* __restrict__ W,
                                              const float* __restrict__ dis,
                                              unsigned int* __restrict__ xwh, int n) {
  __shared__ float Ws[64 * D];   // 32 KB: half of W
  __shared__ float xs[GR * D];   // 16 KB: 32 x-rows

  int row0 = blockIdx.x * GR;
  float4* xs4 = (float4*)xs;
  const float4* x4 = (const float4*)x;
  for (int i = threadIdx.x; i < GR * D / 4; i += 256) {
    int r = i >> 5;
    int gr = row0 + r;
    xs4[i] = (gr < n) ? x4[(size_t)gr * 32 + (i & 31)] : make_float4(0.f, 0.f, 0.f, 0.f);
  }

  int colg = threadIdx.x & 31;
  int rowg = threadIdx.x >> 5;
  float4 acc[4];
#pragma unroll
  for (int r = 0; r < 4; ++r) acc[r] = make_float4(0.f, 0.f, 0.f, 0.f);

  const float4* W4 = (const float4*)W;
  float4* Ws4 = (float4*)Ws;

  for (int half = 0; half < 2; ++half) {
    __syncthreads();
    for (int i = threadIdx.x; i < 64 * D / 4; i += 256)
      Ws4[i] = W4[half * (64 * D / 4) + i];
    __syncthreads();
#pragma unroll
    for (int k4 = 0; k4 < 16; ++k4) {
      float4 xv[4];
#pragma unroll
      for (int r = 0; r < 4; ++r)
        xv[r] = xs4[(rowg * 4 + r) * 32 + half * 16 + k4];
#pragma unroll
      for (int kk = 0; kk < 4; ++kk) {
        float4 w = Ws4[(k4 * 4 + kk) * 32 + colg];
#pragma unroll
        for (int r = 0; r < 4; ++r) {
          float xk = (&xv[r].x)[kk];
          acc[r].x = fmaf(xk, w.x, acc[r].x);
          acc[r].y = fmaf(xk, w.y, acc[r].y);
          acc[r].z = fmaf(xk, w.z, acc[r].z);
          acc[r].w = fmaf(xk, w.w, acc[r].w);
        }
      }
    }
  }

#pragma unroll
  for (int r = 0; r < 4; ++r) {
    int gr = row0 + rowg * 4 + r;
    if (gr < n) {
      float dv = dis[gr];
      uint2 pk;
      pk.x = bf16_round(acc[r].x * dv) | (bf16_round(acc[r].y * dv) << 16);
      pk.y = bf16_round(acc[r].z * dv) | (bf16_round(acc[r].w * dv) << 16);
      *(uint2*)(xwh + (size_t)gr * 64 + colg * 2) = pk;
    }
  }
}

// One wave per node: out[t] = dis[t]*(xwh[t] + sum_j ew_j * xwh[src_j]) + b
__global__ __launch_bounds__(256) void k_gather(const int* __restrict__ rowptr,
                                                const int2* __restrict__ epair,
                                                const unsigned int* __restrict__ xwh,
                                                const float* __restrict__ dis,
                                                const float* __restrict__ b,
                                                float* __restrict__ out, int n) {
  int wid = (blockIdx.x * blockDim.x + threadIdx.x) >> 6;
  int lane = threadIdx.x & 63;
  if (wid >= n) return;
  int beg = rowptr[wid], end = rowptr[wid + 1];
  // self-loop term
  unsigned int u0 = xwh[(size_t)wid * 64 + lane];
  float2 acc;
  acc.x = __uint_as_float(u0 << 16);
  acc.y = __uint_as_float(u0 & 0xffff0000u);
  for (int j0 = beg; j0 < end; j0 += 64) {
    int m = end - j0; if (m > 64) m = 64;
    int2 pr = make_int2(0, 0);
    if (lane < m) pr = epair[j0 + lane];
#pragma unroll 4
    for (int k = 0; k < m; ++k) {
      int s = __shfl(pr.x, k);
      float c = __int_as_float(__shfl(pr.y, k));
      unsigned int u = xwh[(size_t)s * 64 + lane];
      acc.x = fmaf(c, __uint_as_float(u << 16), acc.x);
      acc.y = fmaf(c, __uint_as_float(u & 0xffff0000u), acc.y);
    }
  }
  float dt = dis[wid];
  float2 bb = ((const float2*)b)[lane];
  float2 o;
  o.x = fmaf(dt, acc.x, bb.x);
  o.y = fmaf(dt, acc.y, bb.y);
  ((float2*)out)[(size_t)wid * 64 + lane] = o;
}

extern "C" void kernel_launch(void* const* d_in, const int* in_sizes, int n_in,
                              void* d_out, int out_size, void* d_ws, size_t ws_size,
                              hipStream_t stream) {
  const float* x      = (const float*)d_in[0];
  const int*   ei     = (const int*)d_in[1];
  const float* W      = (const float*)d_in[2];
  const float* b      = (const float*)d_in[3];
  const float* w_pred = (const float*)d_in[4];
  const float* b_pred = (const float*)d_in[5];

  int n = in_sizes[0] / D;
  int E = in_sizes[1] / 2;
  const int* src = ei;       // edge_index[0]
  const int* tgt = ei + E;   // edge_index[1]

  float* out = (float*)d_out;
  float* ws  = (float*)d_ws;
  // workspace layout (4B words)
  unsigned int* xwh = (unsigned int*)ws;        // n*64 (bf16 pairs)
  float* p       = ws + (size_t)n * 64;         // n
  float* q       = p + n;                       // n
  float* dis     = q + n;                       // n
  float* ew      = dis + n;                     // E
  int*   rank    = (int*)(ew + E);              // E
  int2*  epair   = (int2*)(rank + E);           // E pairs (2E words)
  int*   partial = (int*)(epair + E);           // NC*n
  int*   cursor  = partial + (size_t)NC * n;    // NC*n
  int*   cnt     = cursor + (size_t)NC * n;     // n
  int*   rowptr  = cnt + n;                     // n+1
  int*   bsum    = rowptr + n + 1;              // 64
  int*   bpre    = bsum + 64;                   // 64

  int nb = (n + 1023) / 1024;  // scan blocks (<=64 for n<=65536)

  hipMemsetAsync(partial, 0, (size_t)NC * n * sizeof(int), stream);
  k_pq<<<(n + 3) / 4, 256, 0, stream>>>(x, w_pred, p, q, n);
  k_ew_hist<<<(E + 255) / 256, 256, 0, stream>>>(src, tgt, p, q, b_pred, ew, rank, partial, E, n);
  k_reduce<<<(n + 255) / 256, 256, 0, stream>>>(partial, cnt, n);
  k_scan1<<<nb, 256, 0, stream>>>(cnt, rowptr, bsum, n);
  k_scan2<<<1, 64, 0, stream>>>(bsum, bpre, nb);
  k_cursors<<<(n + 255) / 256, 256, 0, stream>>>(rowptr, bpre, partial, cursor, n, E);
  k_fill<<<(E + 255) / 256, 256, 0, stream>>>(src, tgt, ew, rank, cursor, epair, E, n);
  k_deg<<<(n + 255) / 256, 256, 0, stream>>>(rowptr, epair, dis, n);
  k_gemm<<<(n + GR - 1) / GR, 256, 0, stream>>>(x, W, dis, xwh, n);
  k_gather<<<(n + 3) / 4, 256, 0, stream>>>(rowptr, epair, xwh, dis, b, out, n);
}

// Round 6
// 220.236 us; speedup vs baseline: 3.7435x; 1.1199x over previous
//
#include <hip/hip_runtime.h>
#include <math.h>

#define D 128
#define GR 32   // rows per GEMM block
#define NC 16   // privatized histogram copies

__device__ __forceinline__ unsigned int bf16_round(float f) {
  unsigned int u = __float_as_uint(f);
  return (u + 0x7fffu + ((u >> 16) & 1u)) >> 16;  // RNE
}
__device__ __forceinline__ float bf_lo(unsigned int u) { return __uint_as_float(u << 16); }
__device__ __forceinline__ float bf_hi(unsigned int u) { return __uint_as_float(u & 0xffff0000u); }

// p[i] = dot(x[i], w_pred[0:128]); q[i] = dot(x[i], w_pred[128:256])
__global__ __launch_bounds__(256) void k_pq(const float* __restrict__ x,
                                            const float* __restrict__ w_pred,
                                            float* __restrict__ p, float* __restrict__ q,
                                            int n) {
  int wid = (blockIdx.x * blockDim.x + threadIdx.x) >> 6;  // one wave per row
  int lane = threadIdx.x & 63;
  if (wid >= n) return;
  float2 xv = ((const float2*)(x + (size_t)wid * D))[lane];
  float2 wp = ((const float2*)w_pred)[lane];
  float2 wq = ((const float2*)w_pred)[64 + lane];
  float pp = xv.x * wp.x + xv.y * wp.y;
  float qq = xv.x * wq.x + xv.y * wq.y;
#pragma unroll
  for (int off = 32; off > 0; off >>= 1) {
    pp += __shfl_down(pp, off);
    qq += __shfl_down(qq, off);
  }
  if (lane == 0) { p[wid] = pp; q[wid] = qq; }
}

// ew[e] = sigmoid(p[src]+q[tgt]+b_pred); rank[e] = my index within (copy,tgt) cell
__global__ __launch_bounds__(256) void k_ew_hist(const int* __restrict__ src,
                                                 const int* __restrict__ tgt,
                                                 const float* __restrict__ p,
                                                 const float* __restrict__ q,
                                                 const float* __restrict__ b_pred,
                                                 float* __restrict__ ew,
                                                 int* __restrict__ rank,
                                                 int* __restrict__ partial,
                                                 int E, int n) {
  int e = blockIdx.x * blockDim.x + threadIdx.x;
  if (e >= E) return;
  int s = src[e], t = tgt[e];
  float z = p[s] + q[t] + b_pred[0];
  ew[e] = 1.0f / (1.0f + expf(-z));
  int c = (e >> 8) & (NC - 1);
  rank[e] = atomicAdd(&partial[c * n + t], 1);
}

// scan1 (fused reduce): cnt[t]=sum_c partial[c][t]; block-scan 1024 -> rowptr + bsum
__global__ __launch_bounds__(256) void k_scan1(const int* __restrict__ partial,
                                               int* __restrict__ rowptr,
                                               int* __restrict__ bsum, int n) {
  __shared__ int wsum[4];
  int base = blockIdx.x * 1024 + threadIdx.x * 4;
  int4 v = make_int4(0, 0, 0, 0);
  if (base + 3 < n) {
#pragma unroll
    for (int c = 0; c < NC; ++c) {
      int4 t = *(const int4*)(partial + (size_t)c * n + base);
      v.x += t.x; v.y += t.y; v.z += t.z; v.w += t.w;
    }
  } else {
#pragma unroll
    for (int c = 0; c < NC; ++c) {
      const int* pc = partial + (size_t)c * n;
      if (base + 0 < n) v.x += pc[base + 0];
      if (base + 1 < n) v.y += pc[base + 1];
      if (base + 2 < n) v.z += pc[base + 2];
      if (base + 3 < n) v.w += pc[base + 3];
    }
  }
  int s = v.x + v.y + v.z + v.w;
  int lane = threadIdx.x & 63;
  int wave = threadIdx.x >> 6;
  int incl = s;
#pragma unroll
  for (int off = 1; off < 64; off <<= 1) {
    int t = __shfl_up(incl, off);
    if (lane >= off) incl += t;
  }
  if (lane == 63) wsum[wave] = incl;
  __syncthreads();
  int woff = 0;
#pragma unroll
  for (int w = 0; w < 4; ++w) if (w < wave) woff += wsum[w];
  int excl = woff + incl - s;
  if (base + 0 < n) rowptr[base + 0] = excl;
  if (base + 1 < n) rowptr[base + 1] = excl + v.x;
  if (base + 2 < n) rowptr[base + 2] = excl + v.x + v.y;
  if (base + 3 < n) rowptr[base + 3] = excl + v.x + v.y + v.z;
  if (threadIdx.x == 255) bsum[blockIdx.x] = woff + incl;
}

// scan2: single wave exclusive-scans bsum[nb] (nb<=64)
__global__ __launch_bounds__(64) void k_scan2(const int* __restrict__ bsum,
                                              int* __restrict__ bpre, int nb) {
  int lane = threadIdx.x;
  int v = (lane < nb) ? bsum[lane] : 0;
  int incl = v;
#pragma unroll
  for (int off = 1; off < 64; off <<= 1) {
    int t = __shfl_up(incl, off);
    if (lane >= off) incl += t;
  }
  if (lane < nb) bpre[lane] = incl - v;
}

// cursors: finalize rowptr; cursor[c][t] = read-only base of copy c's sub-range
__global__ __launch_bounds__(256) void k_cursors(int* __restrict__ rowptr,
                                                 const int* __restrict__ bpre,
                                                 const int* __restrict__ partial,
                                                 int* __restrict__ cursor,
                                                 int n, int E) {
  int t = blockIdx.x * blockDim.x + threadIdx.x;
  if (t < n) {
    int r = rowptr[t] + bpre[t >> 10];
    rowptr[t] = r;
#pragma unroll
    for (int c = 0; c < NC; ++c) {
      cursor[c * n + t] = r;
      r += partial[c * n + t];
    }
  }
  if (t == 0) rowptr[n] = E;
}

// fill (NO atomics): epair[cursor_base + rank] = (src, ew)
__global__ __launch_bounds__(256) void k_fill(const int* __restrict__ src,
                                              const int* __restrict__ tgt,
                                              const float* __restrict__ ew,
                                              const int* __restrict__ rank,
                                              const int* __restrict__ cursor,
                                              int2* __restrict__ epair, int E, int n) {
  int e = blockIdx.x * blockDim.x + threadIdx.x;
  if (e >= E) return;
  int s = src[e], t = tgt[e];
  int c = (e >> 8) & (NC - 1);
  int pos = cursor[c * n + t] + rank[e];
  epair[pos] = make_int2(s, __float_as_int(ew[e]));
}

// deg[t] = 1 + segmented sum of ew over CSR range; dis = rsqrt(deg)
__global__ __launch_bounds__(256) void k_deg(const int* __restrict__ rowptr,
                                             const int2* __restrict__ epair,
                                             float* __restrict__ dis, int n) {
  int t = blockIdx.x * blockDim.x + threadIdx.x;
  if (t >= n) return;
  int beg = rowptr[t], end = rowptr[t + 1];
  float s = 1.0f;  // self-loop weight
  for (int j = beg; j < end; ++j) s += __int_as_float(epair[j].y);
  dis[t] = (s > 0.0f) ? rsqrtf(s) : 0.0f;
}

// xwh = bf16( dis[row] * (x @ W) )   -- 256 B/row
__global__ __launch_bounds__(256) void k_gemm(const float* __restrict__ x,
                                              const float* __restrict__ W,
                                              const float* __restrict__ dis,
                                              unsigned int* __restrict__ xwh, int n) {
  __shared__ float Ws[64 * D];   // 32 KB: half of W
  __shared__ float xs[GR * D];   // 16 KB: 32 x-rows

  int row0 = blockIdx.x * GR;
  float4* xs4 = (float4*)xs;
  const float4* x4 = (const float4*)x;
  for (int i = threadIdx.x; i < GR * D / 4; i += 256) {
    int r = i >> 5;
    int gr = row0 + r;
    xs4[i] = (gr < n) ? x4[(size_t)gr * 32 + (i & 31)] : make_float4(0.f, 0.f, 0.f, 0.f);
  }

  int colg = threadIdx.x & 31;
  int rowg = threadIdx.x >> 5;
  float4 acc[4];
#pragma unroll
  for (int r = 0; r < 4; ++r) acc[r] = make_float4(0.f, 0.f, 0.f, 0.f);

  const float4* W4 = (const float4*)W;
  float4* Ws4 = (float4*)Ws;

  for (int half = 0; half < 2; ++half) {
    __syncthreads();
    for (int i = threadIdx.x; i < 64 * D / 4; i += 256)
      Ws4[i] = W4[half * (64 * D / 4) + i];
    __syncthreads();
#pragma unroll
    for (int k4 = 0; k4 < 16; ++k4) {
      float4 xv[4];
#pragma unroll
      for (int r = 0; r < 4; ++r)
        xv[r] = xs4[(rowg * 4 + r) * 32 + half * 16 + k4];
#pragma unroll
      for (int kk = 0; kk < 4; ++kk) {
        float4 w = Ws4[(k4 * 4 + kk) * 32 + colg];
#pragma unroll
        for (int r = 0; r < 4; ++r) {
          float xk = (&xv[r].x)[kk];
          acc[r].x = fmaf(xk, w.x, acc[r].x);
          acc[r].y = fmaf(xk, w.y, acc[r].y);
          acc[r].z = fmaf(xk, w.z, acc[r].z);
          acc[r].w = fmaf(xk, w.w, acc[r].w);
        }
      }
    }
  }

#pragma unroll
  for (int r = 0; r < 4; ++r) {
    int gr = row0 + rowg * 4 + r;
    if (gr < n) {
      float dv = dis[gr];
      uint2 pk;
      pk.x = bf16_round(acc[r].x * dv) | (bf16_round(acc[r].y * dv) << 16);
      pk.y = bf16_round(acc[r].z * dv) | (bf16_round(acc[r].w * dv) << 16);
      *(uint2*)(xwh + (size_t)gr * 64 + colg * 2) = pk;
    }
  }
}

// One wave per node; lane = (rg in [0,4), cj in [0,16)).
// Each lane loads uint4 (8 bf16 cols, chunk cj) of source row for edge k+rg:
// one load instruction covers 4 source rows (1 KB/wave). Final shfl_xor
// reduction folds the 4 rg partials; lanes rg==0 write 8 cols each.
__global__ __launch_bounds__(256) void k_gather(const int* __restrict__ rowptr,
                                                const int2* __restrict__ epair,
                                                const uint4* __restrict__ xwh4,
                                                const float* __restrict__ dis,
                                                const float* __restrict__ b,
                                                float* __restrict__ out, int n) {
  int wid = (blockIdx.x * blockDim.x + threadIdx.x) >> 6;
  int lane = threadIdx.x & 63;
  if (wid >= n) return;
  int cj = lane & 15;
  int rg = lane >> 4;
  int beg = rowptr[wid], end = rowptr[wid + 1];

  float acc[8];
  if (rg == 0) {  // self-loop term, counted once
    uint4 v = xwh4[(size_t)wid * 16 + cj];
    acc[0] = bf_lo(v.x); acc[1] = bf_hi(v.x);
    acc[2] = bf_lo(v.y); acc[3] = bf_hi(v.y);
    acc[4] = bf_lo(v.z); acc[5] = bf_hi(v.z);
    acc[6] = bf_lo(v.w); acc[7] = bf_hi(v.w);
  } else {
#pragma unroll
    for (int i = 0; i < 8; ++i) acc[i] = 0.0f;
  }

  for (int j0 = beg; j0 < end; j0 += 64) {
    int m = end - j0; if (m > 64) m = 64;
    int2 pr = make_int2(0, 0);
    if (lane < m) pr = epair[j0 + lane];
    for (int k = 0; k < m; k += 4) {
      int idx = k + rg;
      int s = __shfl(pr.x, idx);
      float c = __int_as_float(__shfl(pr.y, idx));
      if (idx >= m) { s = 0; c = 0.0f; }
      uint4 v = xwh4[(size_t)s * 16 + cj];
      acc[0] = fmaf(c, bf_lo(v.x), acc[0]);
      acc[1] = fmaf(c, bf_hi(v.x), acc[1]);
      acc[2] = fmaf(c, bf_lo(v.y), acc[2]);
      acc[3] = fmaf(c, bf_hi(v.y), acc[3]);
      acc[4] = fmaf(c, bf_lo(v.z), acc[4]);
      acc[5] = fmaf(c, bf_hi(v.z), acc[5]);
      acc[6] = fmaf(c, bf_lo(v.w), acc[6]);
      acc[7] = fmaf(c, bf_hi(v.w), acc[7]);
    }
  }

#pragma unroll
  for (int i = 0; i < 8; ++i) {
    acc[i] += __shfl_xor(acc[i], 16);
    acc[i] += __shfl_xor(acc[i], 32);
  }

  if (rg == 0) {
    float dt = dis[wid];
    float4 b0 = ((const float4*)b)[cj * 2];
    float4 b1 = ((const float4*)b)[cj * 2 + 1];
    float4 o0, o1;
    o0.x = fmaf(dt, acc[0], b0.x); o0.y = fmaf(dt, acc[1], b0.y);
    o0.z = fmaf(dt, acc[2], b0.z); o0.w = fmaf(dt, acc[3], b0.w);
    o1.x = fmaf(dt, acc[4], b1.x); o1.y = fmaf(dt, acc[5], b1.y);
    o1.z = fmaf(dt, acc[6], b1.z); o1.w = fmaf(dt, acc[7], b1.w);
    ((float4*)out)[(size_t)wid * 32 + cj * 2] = o0;
    ((float4*)out)[(size_t)wid * 32 + cj * 2 + 1] = o1;
  }
}

extern "C" void kernel_launch(void* const* d_in, const int* in_sizes, int n_in,
                              void* d_out, int out_size, void* d_ws, size_t ws_size,
                              hipStream_t stream) {
  const float* x      = (const float*)d_in[0];
  const int*   ei     = (const int*)d_in[1];
  const float* W      = (const float*)d_in[2];
  const float* b      = (const float*)d_in[3];
  const float* w_pred = (const float*)d_in[4];
  const float* b_pred = (const float*)d_in[5];

  int n = in_sizes[0] / D;
  int E = in_sizes[1] / 2;
  const int* src = ei;       // edge_index[0]
  const int* tgt = ei + E;   // edge_index[1]

  float* out = (float*)d_out;
  float* ws  = (float*)d_ws;
  // workspace layout (4B words)
  unsigned int* xwh = (unsigned int*)ws;        // n*64 (bf16 pairs)
  float* p       = ws + (size_t)n * 64;         // n
  float* q       = p + n;                       // n
  float* dis     = q + n;                       // n
  float* ew      = dis + n;                     // E
  int*   rank    = (int*)(ew + E);              // E
  int2*  epair   = (int2*)(rank + E);           // E pairs (2E words)
  int*   partial = (int*)(epair + E);           // NC*n
  int*   cursor  = partial + (size_t)NC * n;    // NC*n
  int*   rowptr  = cursor + (size_t)NC * n;     // n+1
  int*   bsum    = rowptr + n + 1;              // 64
  int*   bpre    = bsum + 64;                   // 64

  int nb = (n + 1023) / 1024;  // scan blocks (<=64 for n<=65536)

  (void)hipMemsetAsync(partial, 0, (size_t)NC * n * sizeof(int), stream);
  k_pq<<<(n + 3) / 4, 256, 0, stream>>>(x, w_pred, p, q, n);
  k_ew_hist<<<(E + 255) / 256, 256, 0, stream>>>(src, tgt, p, q, b_pred, ew, rank, partial, E, n);
  k_scan1<<<nb, 256, 0, stream>>>(partial, rowptr, bsum, n);
  k_scan2<<<1, 64, 0, stream>>>(bsum, bpre, nb);
  k_cursors<<<(n + 255) / 256, 256, 0, stream>>>(rowptr, bpre, partial, cursor, n, E);
  k_fill<<<(E + 255) / 256, 256, 0, stream>>>(src, tgt, ew, rank, cursor, epair, E, n);
  k_deg<<<(n + 255) / 256, 256, 0, stream>>>(rowptr, epair, dis, n);
  k_gemm<<<(n + GR - 1) / GR, 256, 0, stream>>>(x, W, dis, xwh, n);
  k_gather<<<(n + 3) / 4, 256, 0, stream>>>(rowptr, epair, (const uint4*)xwh, dis, b, out, n);
}